// Round 2
// baseline (596.099 us; speedup 1.0000x reference)
//
#include <hip/hip_runtime.h>
#include <hip/hip_bf16.h>
#include <cstdint>

typedef __bf16 bf16x8 __attribute__((ext_vector_type(8)));
typedef unsigned short ushortx8 __attribute__((ext_vector_type(8)));
typedef unsigned short ushortx4 __attribute__((ext_vector_type(4)));
typedef float f32x4 __attribute__((ext_vector_type(4)));

constexpr int Cc  = 512;       // channels
constexpr int Ssp = 3136;      // 56*56 spatial per image
constexpr float NINV = 1.f / 100352.f;   // 1/(32*3136)

__device__ __forceinline__ unsigned short f2bf(float f) {
    union { float f; unsigned u; } a; a.f = f;
    unsigned u = a.u;
    unsigned r = u + 0x7fffu + ((u >> 16) & 1u);   // RNE
    return (unsigned short)(r >> 16);
}
__device__ __forceinline__ float bf2f(unsigned short h) {
    union { unsigned u; float f; } a; a.u = ((unsigned)h) << 16;
    return a.f;
}
__device__ __forceinline__ float tanh_fast(float u) {
    // 1 - 2/(e^{2u}+1): monotone, saturates to +-1 without NaN
    float e = __expf(2.f * u);
    return 1.f - 2.f / (e + 1.f);
}
// LDS k-swizzle (8-element chunks XORed by row bits) to kill staging bank conflicts
__device__ __forceinline__ int swz(int row, int k) {
    return k ^ (((row >> 2) & 7) << 3);
}

// ---------------- K0: fc_w fp32 -> bf16 ----------------
__global__ void kWconv(const float* __restrict__ w, unsigned short* __restrict__ wb) {
    int i = (blockIdx.x * 256 + threadIdx.x) * 4;
    float4 v = *(const float4*)(w + i);
    ushortx4 o;
    o[0] = f2bf(v.x); o[1] = f2bf(v.y); o[2] = f2bf(v.z); o[3] = f2bf(v.w);
    *(ushortx4*)(wb + i) = o;
}

// ---------------- KA: GEMM(+residual+bias) fused with Gram+tanh+stats ----------------
__global__ __launch_bounds__(512) void kA(
    const float* __restrict__ x, const unsigned short* __restrict__ wb,
    const float* __restrict__ fcb, float* __restrict__ sbuf,
    float* __restrict__ gstats)
{
    __shared__ __attribute__((aligned(16))) unsigned short xl[64 * 72];   // [s][k] bf16, pitch 72
    __shared__ __attribute__((aligned(16))) unsigned short tl[64 * 520];  // [s][c] bf16, pitch 520
    __shared__ float statsl[512];

    const int tid  = threadIdx.x;
    const int wave = tid >> 6;
    const int lane = tid & 63;
    const int lg   = lane >> 4;
    const int lm   = lane & 15;

    const int blk = blockIdx.x;
    const int b   = blk / 49;
    const int sc  = blk % 49;
    const float* xA = x + (size_t)b * Cc * Ssp + sc * 64;   // + k*3136 + s

    f32x4 acc[4][4];
#pragma unroll
    for (int mi = 0; mi < 4; ++mi)
#pragma unroll
        for (int ni = 0; ni < 4; ++ni) acc[mi][ni] = (f32x4){0.f, 0.f, 0.f, 0.f};

    float bias[4];
#pragma unroll
    for (int ni = 0; ni < 4; ++ni) bias[ni] = fcb[wave * 64 + ni * 16 + lm];

    const int stid = tid >> 4;         // 0..31 (k-row within half-tile)
    const int s4   = (tid & 15) * 4;   // s quad

    for (int kt = 0; kt < 8; ++kt) {
        // ---- stage x tile kt: [64 k][64 s] fp32 -> LDS [s][k] bf16 (transposed) ----
#pragma unroll
        for (int it = 0; it < 2; ++it) {
            int kr = stid + it * 32;
            float4 v = *(const float4*)(xA + (size_t)(kt * 64 + kr) * Ssp + s4);
#pragma unroll
            for (int i = 0; i < 4; ++i) {
                int row = s4 + i;
                xl[row * 72 + swz(row, kr)] = f2bf(((const float*)&v)[i]);
            }
        }
        __syncthreads();

        // ---- residual add: wave kt owns c-range == this tile's k-range ----
        if (wave == kt) {
#pragma unroll
            for (int mi = 0; mi < 4; ++mi)
#pragma unroll
                for (int ni = 0; ni < 4; ++ni) {
                    int kl = ni * 16 + lm;
#pragma unroll
                    for (int j = 0; j < 4; ++j) {
                        int row = mi * 16 + lg * 4 + j;
                        acc[mi][ni][j] += bf2f(xl[row * 72 + swz(row, kl)]);
                    }
                }
        }

        // ---- MFMA: 2 k-steps of 32 ----
#pragma unroll
        for (int ks = 0; ks < 2; ++ks) {
            bf16x8 af[4], bfr[4];
#pragma unroll
            for (int mi = 0; mi < 4; ++mi) {
                int row = mi * 16 + lm;
                int k0  = swz(row, ks * 32 + 8 * lg);
                af[mi] = *(const bf16x8*)&xl[row * 72 + k0];
            }
#pragma unroll
            for (int ni = 0; ni < 4; ++ni) {
                int c = wave * 64 + ni * 16 + lm;
                bfr[ni] = *(const bf16x8*)(wb + (size_t)c * 512 + kt * 64 + ks * 32 + 8 * lg);
            }
#pragma unroll
            for (int mi = 0; mi < 4; ++mi)
#pragma unroll
                for (int ni = 0; ni < 4; ++ni)
                    acc[mi][ni] = __builtin_amdgcn_mfma_f32_16x16x32_bf16(
                        af[mi], bfr[ni], acc[mi][ni], 0, 0, 0);
        }
        __syncthreads();
    }

    // ---- epilogue: t = acc + bias -> LDS [s][c] bf16 ----
#pragma unroll
    for (int mi = 0; mi < 4; ++mi)
#pragma unroll
        for (int ni = 0; ni < 4; ++ni) {
            int c = wave * 64 + ni * 16 + lm;
#pragma unroll
            for (int j = 0; j < 4; ++j) {
                int srow = mi * 16 + lg * 4 + j;
                tl[srow * 520 + c] = f2bf(acc[mi][ni][j] + bias[ni]);
            }
        }
    statsl[tid] = 0.f;
    __syncthreads();

    // ---- phase 2: per-n Gram via mfma(f, f, 0); identical A/B frags => layout-safe ----
    float sum[4] = {0, 0, 0, 0}, ssq[4] = {0, 0, 0, 0};
    const size_t nbase = (size_t)b * Ssp + sc * 64;
    for (int nn = 0; nn < 8; ++nn) {
        int nl = wave * 8 + nn;
        ushortx8 uf;
#pragma unroll
        for (int bs = 0; bs < 8; ++bs) {
            int cidx = (bs * 4 + lg) * 16 + lm;   // c = g*16 + p, p = lm, slot->g map
            uf[bs] = tl[nl * 520 + cidx];
        }
        bf16x8 f = __builtin_bit_cast(bf16x8, uf);
        f32x4 d = __builtin_amdgcn_mfma_f32_16x16x32_bf16(f, f, (f32x4){0, 0, 0, 0}, 0, 0, 0);
        float* sp = sbuf + (nbase + nl) * 256;
#pragma unroll
        for (int j = 0; j < 4; ++j) {
            float sv = tanh_fast(d[j] * (1.f / 32.f));
            sum[j] += sv; ssq[j] += sv * sv;
            sp[(lg * 4 + j) * 16 + lm] = sv;      // s[n, p*16+q]
        }
    }
#pragma unroll
    for (int j = 0; j < 4; ++j) {
        int pq = (lg * 4 + j) * 16 + lm;
        atomicAdd(&statsl[pq], sum[j]);
        atomicAdd(&statsl[256 + pq], ssq[j]);
    }
    __syncthreads();
    if (tid < 256) {
        atomicAdd(&gstats[tid], statsl[tid]);
        atomicAdd(&gstats[256 + tid], statsl[256 + tid]);
    }
}

// ---------------- KB: finalize BN stats ----------------
__global__ void kB(const float* __restrict__ gstats, float* __restrict__ minv) {
    int t = threadIdx.x;
    float mean = gstats[t] * NINV;
    float var  = gstats[256 + t] * NINV - mean * mean;   // biased var
    minv[t]       = mean;
    minv[256 + t] = rsqrtf(var + 1e-5f);
}

// ---------------- KC: out = x + BN(s)[c>>1] ----------------
// 32 spatial rows per block: LDS 33 KB -> 4 blocks/CU (16 waves) for latency hiding.
__global__ __launch_bounds__(256) void kC(
    const float* __restrict__ x, const float* __restrict__ sbuf,
    const float* __restrict__ minv, const float* __restrict__ gamma,
    const float* __restrict__ beta, float* __restrict__ out)
{
    __shared__ __attribute__((aligned(16))) float sl[32 * 260];  // [n][pq] pitch 260
    const int tid = threadIdx.x;
    const int blk = blockIdx.x;
    const int b = blk / 98, sc = blk % 98;

    const float* sb = sbuf + ((size_t)b * Ssp + sc * 32) * 256;
#pragma unroll
    for (int i = 0; i < 8; ++i) {
        int flat = (i * 256 + tid) * 4;
        float4 v = *(const float4*)(sb + flat);
        int n = flat >> 8, pq = flat & 255;
        *(float4*)&sl[n * 260 + pq] = v;
    }
    __syncthreads();

    const size_t xoff = (size_t)b * Cc * Ssp + sc * 32;
    const float* xb = x + xoff;
    float* ob = out + xoff;
    for (int iter = 0; iter < 16; ++iter) {
        int task = iter * 256 + tid;
        int c  = task >> 3;           // 512 channels
        int s4 = (task & 7) * 4;      // 8 quads x 4 = 32 spatial
        int pq = c >> 1;
        float m = minv[pq], inv = minv[256 + pq];
        float ga = gamma[c] * inv;
        float be = beta[c] - m * ga;
        float4 xv = *(const float4*)(xb + (size_t)c * Ssp + s4);
        float4 r;
        r.x = xv.x + sl[(s4 + 0) * 260 + pq] * ga + be;
        r.y = xv.y + sl[(s4 + 1) * 260 + pq] * ga + be;
        r.z = xv.z + sl[(s4 + 2) * 260 + pq] * ga + be;
        r.w = xv.w + sl[(s4 + 3) * 260 + pq] * ga + be;
        *(float4*)(ob + (size_t)c * Ssp + s4) = r;
    }
}

extern "C" void kernel_launch(void* const* d_in, const int* in_sizes, int n_in,
                              void* d_out, int out_size, void* d_ws, size_t ws_size,
                              hipStream_t stream) {
    const float* x     = (const float*)d_in[0];
    const float* fcw   = (const float*)d_in[1];
    const float* fcb   = (const float*)d_in[2];
    const float* gamma = (const float*)d_in[3];
    const float* beta  = (const float*)d_in[4];
    float* out = (float*)d_out;

    char* ws = (char*)d_ws;
    unsigned short* wb = (unsigned short*)ws;                  // 512 KB bf16 weights
    float* gstats = (float*)(ws + 512 * 512 * 2);              // 512 floats (sum, sumsq)
    float* minv   = (float*)(ws + 512 * 512 * 2 + 2048);       // 512 floats (mean, inv)
    float* sbuf   = (float*)(ws + (1 << 20));                  // 100352*256 floats (~98 MB)

    hipMemsetAsync(gstats, 0, 2048, stream);
    kWconv<<<dim3(256), dim3(256), 0, stream>>>(fcw, wb);
    kA<<<dim3(1568), dim3(512), 0, stream>>>(x, wb, fcb, sbuf, gstats);
    kB<<<dim3(1), dim3(256), 0, stream>>>(gstats, minv);
    kC<<<dim3(3136), dim3(256), 0, stream>>>(x, sbuf, minv, gamma, beta, out);
}